// Round 6
// baseline (157.107 us; speedup 1.0000x reference)
//
#include <hip/hip_runtime.h>
#include <hip/hip_bf16.h>
#include <math.h>

// Problem constants (fixed by setup_inputs)
#define NX 192
#define NY 192
#define NPIX (NX * NY)     // 36864
#define ETLN 16
#define DATOMS 4000
#define SCH 10             // atom chunks (grid.y)
#define CHUNK 400          // atoms per chunk (25 tiles, odd -> 12 pairs + 1)
#define CHB (CHUNK * 64)   // chunk bytes = 25600
#define PXB (NPIX / 128)   // 288 pixel blocks (128 px/block, 32 px/wave)

typedef __attribute__((ext_vector_type(8))) short short8;
typedef __attribute__((ext_vector_type(4))) float f32x4;
typedef unsigned short ushort;
typedef unsigned int uint;
typedef unsigned long long u64;

// ---- ws layout (bytes) ----
// A1   : 4000*64 = 256000   atom rows, TILE-SLICE-MAJOR layout per chunk:
//                           [chunk][tile][slice s=0..3][row r=0..15] x 16B
// PART : SCH*NPIX*8 = 2949120  per-(chunk,px) u64 keys, plain stores
#define OFF_A1   0
#define OFF_PART 256000

// R14: fusing finalize into match regressed -> keep separate.
// R17 FAILED: XOR-swizzled LDS (unverified algebra). R19: tile-slice-major
// A1 + plain copy staging + conflict-free reads: conflicts 3.25M -> 0.37M
// but only -2us (44->42). LESSON: interior of the loop is NOT the
// constraint. Counters: MfmaUtil 16%, VALUBusy 45%, Occupancy 24% =
// latency-bound, occupancy-capped by the 51.2KB LDS tile (3 blocks/CU).
// R20 (this round): CHUNK 800->400, SCH 5->10. LDS 25.6KB -> 6 blocks/CU
// = 24 waves/CU (2x wave supply). Same total work (2x blocks, 1/2 work
// each); CT=25 odd -> 5 ping-pong iters + 2 tail pairs + 1 single tile
// (top2_update4). Data path byte-identical to R19 otherwise.

__device__ __forceinline__ int mask_and_z(const float* __restrict__ delta_ms,
                                          float* mask) {
    int z = -1;
#pragma unroll
    for (int e = 0; e < ETLN; ++e) {
        float m = (delta_ms[e] * 1e-3f < 1e-3f) ? 1.0f : 0.0f;
        mask[e] = m;
        if (m == 0.0f && z < 0) z = e;
    }
    return z;
}

// bf16 split: returns bf16 bits of x (RN); *rem = x - float(bf16(x)) (exact)
__device__ __forceinline__ ushort bfsplit(float x, float* rem) {
    __hip_bfloat16 h = __float2bfloat16(x);
    *rem = x - __bfloat162float(h);
    union { __hip_bfloat16 h; ushort u; } cv;
    cv.h = h;
    return cv.u;
}

// Two-stage normalize -> t = -2*s, sentinel t[z]=1 via SELECT (R4 lesson:
// no dynamic-index alloca stores). Reciprocal-mul: 2 divides total.
__device__ __forceinline__ void compute_t(const float* __restrict__ row,
                                          const float* mask, int z,
                                          float* tv, float* s2out) {
    float x[ETLN];
    const float4* r4 = (const float4*)row;
#pragma unroll
    for (int q = 0; q < 4; ++q) {
        float4 a = r4[q];
        x[4 * q + 0] = a.x; x[4 * q + 1] = a.y;
        x[4 * q + 2] = a.z; x[4 * q + 3] = a.w;
    }
    float n1s = 0.f;
#pragma unroll
    for (int e = 0; e < ETLN; ++e) n1s += x[e] * x[e];
    float n1 = sqrtf(n1s);
    float inv1 = (n1 > 0.f) ? (1.0f / n1) : 0.f;
#pragma unroll
    for (int e = 0; e < ETLN; ++e) x[e] = x[e] * inv1 * mask[e];
    float n2s = 0.f;
#pragma unroll
    for (int e = 0; e < ETLN; ++e) n2s += x[e] * x[e];
    float n2 = sqrtf(n2s);
    float inv2 = (n2 > 0.f) ? (1.0f / n2) : 0.f;
    float s2 = 0.f;
#pragma unroll
    for (int e = 0; e < ETLN; ++e) {
        float y = x[e] * inv2;
        s2 += y * y;
        float t = -2.0f * y;
        tv[e] = (e == z) ? 1.0f : t;
    }
    *s2out = s2;
}

// atom row: mask -> normalize -> d2 in sentinel col (exact prep semantics)
__device__ __forceinline__ void atom_row(const float* __restrict__ row,
                                         const float* mask, int z, float* w) {
    float v[ETLN];
    const float4* q4 = (const float4*)row;
#pragma unroll
    for (int q = 0; q < 4; ++q) {
        float4 a = q4[q];
        v[4 * q + 0] = a.x * mask[4 * q + 0];
        v[4 * q + 1] = a.y * mask[4 * q + 1];
        v[4 * q + 2] = a.z * mask[4 * q + 2];
        v[4 * q + 3] = a.w * mask[4 * q + 3];
    }
    float ss = 0.f;
#pragma unroll
    for (int e = 0; e < ETLN; ++e) ss += v[e] * v[e];
    float n = sqrtf(ss);
    float inv = (n > 0.f) ? (1.0f / n) : 0.f;
    float d2 = 0.f;
#pragma unroll
    for (int e = 0; e < ETLN; ++e) {
        float y = v[e] * inv;
        v[e] = y;
        d2 += y * y;
    }
#pragma unroll
    for (int e = 0; e < ETLN; ++e) w[e] = (e == z) ? d2 : v[e];
}

// bf16 2-way split row -> 16 packed dwords, slice order:
// fd[0..3]=Ah[0:8] fd[4..7]=Ah[8:16] fd[8..11]=Am[0:8] fd[12..15]=Am[8:16]
__device__ __forceinline__ void pack_row16(const float* w, uint* fd) {
    uint hb[ETLN], mb[ETLN];
#pragma unroll
    for (int e = 0; e < ETLN; ++e) {
        float r1, dmy;
        hb[e] = (uint)bfsplit(w[e], &r1);
        mb[e] = (uint)bfsplit(r1, &dmy);
    }
#pragma unroll
    for (int k = 0; k < 4; ++k) {
        fd[k]      = hb[2 * k]     | (hb[2 * k + 1] << 16);
        fd[4 + k]  = hb[8 + 2 * k] | (hb[9 + 2 * k] << 16);
        fd[8 + k]  = mb[2 * k]     | (mb[2 * k + 1] << 16);
        fd[12 + k] = mb[8 + 2 * k] | (mb[8 + 2 * k + 1] << 16);
    }
}

// prep_atoms: 4000 threads -> A1 in tile-slice-major layout (~1-2us)
__global__ __launch_bounds__(256) void prep_atoms(
        const float* __restrict__ db_mag, const float* __restrict__ delta_ms,
        char* __restrict__ A1) {
    int t = blockIdx.x * 256 + threadIdx.x;
    if (t >= DATOMS) return;
    float mask[ETLN];
    int z = mask_and_z(delta_ms, mask);
    float w[ETLN];
    atom_row(db_mag + (size_t)t * ETLN, mask, z, w);
    uint fd[16];
    pack_row16(w, fd);
    int chunk = t / CHUNK, jj = t % CHUNK;
    int tile = jj >> 4, row = jj & 15;
    char* base = A1 + (size_t)chunk * CHB + tile * 1024 + row * 16;
#pragma unroll
    for (int s = 0; s < 4; ++s)
        *(uint4*)(base + s * 256) = make_uint4(fd[4 * s], fd[4 * s + 1],
                                               fd[4 * s + 2], fd[4 * s + 3]);
}

// identity 64B row store (4x b128) -- pixel scratch only
__device__ __forceinline__ void store_row16(char* rowbase, const uint* fd) {
#pragma unroll
    for (int s = 0; s < 4; ++s) {
        ((uint4*)rowbase)[s] = make_uint4(fd[4 * s], fd[4 * s + 1],
                                          fd[4 * s + 2], fd[4 * s + 3]);
    }
}

// Approx filter key (R16-verified): single v_and_or_b32 key, octet-min.
__device__ __forceinline__ void top2_update8(f32x4 aLo, f32x4 aHi,
                                             uint i0, uint i1, uint i2, uint i3,
                                             uint* k1, uint* k2) {
    uint kk0 = (__float_as_uint(aLo[0]) & 0xFFFFF000u) | i0;
    uint kk1 = (__float_as_uint(aLo[1]) & 0xFFFFF000u) | i1;
    uint kk2 = (__float_as_uint(aLo[2]) & 0xFFFFF000u) | i2;
    uint kk3 = (__float_as_uint(aLo[3]) & 0xFFFFF000u) | i3;
    uint kk4 = (__float_as_uint(aHi[0]) & 0xFFFFF000u) | (i0 + 16u);
    uint kk5 = (__float_as_uint(aHi[1]) & 0xFFFFF000u) | (i1 + 16u);
    uint kk6 = (__float_as_uint(aHi[2]) & 0xFFFFF000u) | (i2 + 16u);
    uint kk7 = (__float_as_uint(aHi[3]) & 0xFFFFF000u) | (i3 + 16u);
    uint t = min(min(min(kk0, kk1), min(kk2, kk3)),
                 min(min(kk4, kk5), min(kk6, kk7)));
    bool lt = t < *k1;
    uint mn2 = min(*k2, t);
    *k2 = lt ? *k1 : mn2;
    *k1 = min(*k1, t);
}

// 4-value variant for the odd single-tile tail (quartet-min candidate).
__device__ __forceinline__ void top2_update4(f32x4 a, uint i0, uint i1,
                                             uint i2, uint i3,
                                             uint* k1, uint* k2) {
    uint kk0 = (__float_as_uint(a[0]) & 0xFFFFF000u) | i0;
    uint kk1 = (__float_as_uint(a[1]) & 0xFFFFF000u) | i1;
    uint kk2 = (__float_as_uint(a[2]) & 0xFFFFF000u) | i2;
    uint kk3 = (__float_as_uint(a[3]) & 0xFFFFF000u) | i3;
    uint t = min(min(kk0, kk1), min(kk2, kk3));
    bool lt = t < *k1;
    uint mn2 = min(*k2, t);
    *k2 = lt ? *k1 : mn2;
    *k1 = min(*k1, t);
}

// Score one 2-tile pair (32 atoms x 32 pixels): 8 MFMA + 2 top2_update8.
__device__ __forceinline__ void proc_pair(
        short8 t0, short8 t1, short8 V1A, short8 V2A, short8 V1B, short8 V2B,
        f32x4 cinit, uint i0, uint i1, uint i2, uint i3,
        uint* k1A, uint* k2A, uint* k1B, uint* k2B) {
    f32x4 a00 = __builtin_amdgcn_mfma_f32_16x16x32_bf16(t0, V1A, cinit, 0, 0, 0);
    f32x4 a01 = __builtin_amdgcn_mfma_f32_16x16x32_bf16(t0, V1B, cinit, 0, 0, 0);
    f32x4 a10 = __builtin_amdgcn_mfma_f32_16x16x32_bf16(t1, V1A, cinit, 0, 0, 0);
    f32x4 a11 = __builtin_amdgcn_mfma_f32_16x16x32_bf16(t1, V1B, cinit, 0, 0, 0);
    a00 = __builtin_amdgcn_mfma_f32_16x16x32_bf16(t0, V2A, a00, 0, 0, 0);
    a01 = __builtin_amdgcn_mfma_f32_16x16x32_bf16(t0, V2B, a01, 0, 0, 0);
    a10 = __builtin_amdgcn_mfma_f32_16x16x32_bf16(t1, V2A, a10, 0, 0, 0);
    a11 = __builtin_amdgcn_mfma_f32_16x16x32_bf16(t1, V2B, a11, 0, 0, 0);
    asm("" : "+v"(a00), "+v"(a01), "+v"(a10), "+v"(a11));
    top2_update8(a00, a10, i0, i1, i2, i3, k1A, k2A);   // pixel set A
    top2_update8(a01, a11, i0, i1, i2, i3, k1B, k2B);   // pixel set B
}

// Score one single tile (16 atoms x 32 px): 4 MFMA + 2 top2_update4.
__device__ __forceinline__ void proc_single(
        short8 t0, short8 V1A, short8 V2A, short8 V1B, short8 V2B,
        f32x4 cinit, uint i0, uint i1, uint i2, uint i3,
        uint* k1A, uint* k2A, uint* k1B, uint* k2B) {
    f32x4 a00 = __builtin_amdgcn_mfma_f32_16x16x32_bf16(t0, V1A, cinit, 0, 0, 0);
    f32x4 a01 = __builtin_amdgcn_mfma_f32_16x16x32_bf16(t0, V1B, cinit, 0, 0, 0);
    a00 = __builtin_amdgcn_mfma_f32_16x16x32_bf16(t0, V2A, a00, 0, 0, 0);
    a01 = __builtin_amdgcn_mfma_f32_16x16x32_bf16(t0, V2B, a01, 0, 0, 0);
    asm("" : "+v"(a00), "+v"(a01));
    top2_update4(a00, i0, i1, i2, i3, k1A, k2A);
    top2_update4(a01, i0, i1, i2, i3, k1B, k2B);
}

// Monotone total-order map for signed f32 (R9-verified selection semantics).
__device__ __forceinline__ uint fmono(float f) {
    uint b = __float_as_uint(f);
    return b ^ (uint)(((int)b >> 31) | 0x80000000);
}

// match_fused: pixel frags in-wave via LDS scratch (first 8KB, identity
// layout); atom chunk copied A1->LDS (coalesced uint4 + contiguous
// ds_write_b128); main loop reads tiles at quad*256 + l15*16 (contiguous
// 1KB/wave-tile, conflict-free); ping-pong pipeline; epilogue rescores
// exact atoms from db_mag; plain store to partial[chunk][px].
// LDS 25.6KB -> 6 blocks/CU = 24 waves/CU (R20 occupancy lever).
__global__ __launch_bounds__(256, 6) void match_fused(
        const float* __restrict__ sig, const float* __restrict__ db_mag,
        const float* __restrict__ delta_ms, const char* __restrict__ A1,
        u64* __restrict__ partial) {
    __shared__ __align__(1024) char smem[CHB];   // 25600 B

    const int lane = threadIdx.x & 63;
    const int wv   = threadIdx.x >> 6;
    const int quad = lane >> 4;
    const int l15  = lane & 15;
    const int pl   = lane & 31;

    float mask[ETLN];
    int z = mask_and_z(delta_ms, mask);

    // ---- pixel phase: all lanes compute pixel wbase+(lane&31) ----
    const int wbase = blockIdx.x * 128 + wv * 32;
    float tv[ETLN], s2px;
    compute_t(sig + (size_t)(wbase + pl) * ETLN, mask, z, tv, &s2px);
    {
        uint fd[16];
        pack_row16(tv, fd);
        if (lane < 32) store_row16(smem + wv * 2048 + pl * 64, fd);
    }
    __syncthreads();

    // V1 = slice[quad] at quad*16; V2 = slice[quad^2] (R18-verified offsets)
    const char* pb = smem + wv * 2048 + l15 * 64;
    short8 V1A = *(const short8*)(pb + quad * 16);
    short8 V2A = *(const short8*)(pb + (quad ^ 2) * 16);
    short8 V1B = *(const short8*)(pb + 1024 + quad * 16);
    short8 V2B = *(const short8*)(pb + 1024 + (quad ^ 2) * 16);
    asm("" : "+v"(V1A), "+v"(V2A), "+v"(V1B), "+v"(V2B));
    __syncthreads();   // frag reads drained before copy overwrites scratch

    // ---- atom stage: plain copy A1 chunk -> LDS (layout already final) ----
    const char* src = A1 + (size_t)blockIdx.y * CHB;
    for (int r = 0; r < 7; ++r) {
        int c = (int)threadIdx.x + r * 256;
        if (c < CHB / 16) {
            uint4 v = *(const uint4*)(src + (size_t)c * 16);
            *(uint4*)(smem + (size_t)c * 16) = v;
        }
    }
    __syncthreads();

    // ---- main loop: ping-pong; conflict-free reads (contiguous 1KB) ----
    // CT=25 tiles: prime 4 + 5 iters (4 tiles each) + 2 tail pairs + single
    uint k1A = 0xFFFFFFFFu, k2A = 0xFFFFFFFFu;
    uint k1B = 0xFFFFFFFFu, k2B = 0xFFFFFFFFu;
    const f32x4 cinit = (f32x4){1.0f, 1.0f, 1.0f, 1.0f};   // f' = dist^2

    const int jbase = blockIdx.y * CHUNK;
    const char* abase = smem + quad * 256 + l15 * 16;
    uint i0 = (uint)(jbase + quad * 4);
    uint i1 = i0 + 1u, i2 = i0 + 2u, i3 = i0 + 3u;

    short8 x0 = *(const short8*)(abase);
    short8 x1 = *(const short8*)(abase + 1024);
    short8 y0 = *(const short8*)(abase + 2048);
    short8 y1 = *(const short8*)(abase + 3072);
    const char* W = abase + 4096;

#pragma unroll 1
    for (int it = 0; it < 5; ++it) {
        asm("" : "+v"(x0), "+v"(x1));
        proc_pair(x0, x1, V1A, V2A, V1B, V2B, cinit, i0, i1, i2, i3,
                  &k1A, &k2A, &k1B, &k2B);
        i0 += 32u; i1 += 32u; i2 += 32u; i3 += 32u;
        x0 = *(const short8*)(W);            // tiles 4it+4, 4it+5
        x1 = *(const short8*)(W + 1024);
        asm("" : "+v"(y0), "+v"(y1));
        proc_pair(y0, y1, V1A, V2A, V1B, V2B, cinit, i0, i1, i2, i3,
                  &k1A, &k2A, &k1B, &k2B);
        i0 += 32u; i1 += 32u; i2 += 32u; i3 += 32u;
        y0 = *(const short8*)(W + 2048);     // tiles 4it+6, 4it+7
        y1 = *(const short8*)(W + 3072);
        W += 4096;
    }
    // tail: x = tiles 20,21; y = 22,23; W -> tile 24
    proc_pair(x0, x1, V1A, V2A, V1B, V2B, cinit, i0, i1, i2, i3,
              &k1A, &k2A, &k1B, &k2B);
    i0 += 32u; i1 += 32u; i2 += 32u; i3 += 32u;
    proc_pair(y0, y1, V1A, V2A, V1B, V2B, cinit, i0, i1, i2, i3,
              &k1A, &k2A, &k1B, &k2B);
    i0 += 32u; i1 += 32u; i2 += 32u; i3 += 32u;
    short8 z0 = *(const short8*)(W);
    proc_single(z0, V1A, V2A, V1B, V2B, cinit, i0, i1, i2, i3,
                &k1A, &k2A, &k1B, &k2B);

    // ---- epilogue: cross-quad top-2 merge, EXACT rescore from db_mag ----
    float tvB[ETLN], s2B;
#pragma unroll
    for (int e = 0; e < ETLN; ++e) tvB[e] = __shfl(tv[e], lane + 16);
    s2B = __shfl(s2px, lane + 16);

#pragma unroll
    for (int g = 0; g < 2; ++g) {
        uint p1 = g ? k1B : k1A;
        uint p2 = g ? k2B : k2A;
#pragma unroll
        for (int off = 16; off <= 32; off <<= 1) {
            uint o1 = (uint)__shfl_xor((int)p1, off);
            uint o2 = (uint)__shfl_xor((int)p2, off);
            uint n1 = p1 < o1 ? p1 : o1;
            uint mx = p1 < o1 ? o1 : p1;
            uint mn = p2 < o2 ? p2 : o2;
            p2 = mx < mn ? mx : mn;
            p1 = n1;
        }
        if (lane < 16) {
            int px = wbase + lane + (g ? 16 : 0);
            int j1 = (int)(p1 & 0xFFFu);
            int j2 = (int)(p2 & 0xFFFu);
            const float* tvx = g ? tvB : tv;
            float sx = g ? s2B : s2px;
            float w1[ETLN], w2[ETLN];
            atom_row(db_mag + (size_t)j1 * ETLN, mask, z, w1);
            atom_row(db_mag + (size_t)j2 * ETLN, mask, z, w2);
            float f1 = 0.f, f2 = 0.f;
#pragma unroll
            for (int e = 0; e < ETLN; ++e) {
                f1 = fmaf(w1[e], tvx[e], f1);
                f2 = fmaf(w2[e], tvx[e], f2);
            }
            u64 key1 = (((u64)fmono(f1 + sx)) << 32) | (uint)j1;
            u64 key2 = (((u64)fmono(f2 + sx)) << 32) | (uint)j2;
            partial[(size_t)blockIdx.y * NPIX + px] =
                key1 < key2 ? key1 : key2;
        }
    }
}

// finalize: min over 10 chunk keys, decode (monotone bits of f+s2, j)
__global__ __launch_bounds__(256) void finalize(
        const u64* __restrict__ partial, const float* __restrict__ t2s,
        const float* __restrict__ b1s, float* __restrict__ out) {
    int p = blockIdx.x * 256 + threadIdx.x;
    if (p >= NPIX) return;
    u64 m = partial[p];
#pragma unroll
    for (int c = 1; c < SCH; ++c) {
        u64 v = partial[(size_t)c * NPIX + p];
        m = v < m ? v : m;
    }
    int j = (int)(m & 0xFFFu);
    uint mb = (uint)(m >> 32);
    uint b = (mb & 0x80000000u) ? (mb ^ 0x80000000u) : ~mb;  // fmono^-1
    float val = __uint_as_float(b);                          // = f + s2
    out[p] = t2s[j];
    out[NPIX + p] = b1s[j];
    out[2 * NPIX + p] = sqrtf(fmaxf(val, 0.0f));
}

extern "C" void kernel_launch(void* const* d_in, const int* in_sizes, int n_in,
                              void* d_out, int out_size, void* d_ws, size_t ws_size,
                              hipStream_t stream) {
    const float* sig    = (const float*)d_in[0];  // [192,192,16]
    const float* db_mag = (const float*)d_in[1];  // [4000,16]
    const float* t2s    = (const float*)d_in[2];  // [4000]
    const float* b1s    = (const float*)d_in[3];  // [4000]
    const float* delta  = (const float*)d_in[4];  // [16]

    char* ws = (char*)d_ws;
    char* A1      = ws + OFF_A1;
    u64*  partial = (u64*)(ws + OFF_PART);

    prep_atoms<<<(DATOMS + 255) / 256, 256, 0, stream>>>(db_mag, delta, A1);
    dim3 grid(PXB, SCH);
    match_fused<<<grid, 256, 0, stream>>>(sig, db_mag, delta, A1, partial);
    finalize<<<PXB / 2, 256, 0, stream>>>(partial, t2s, b1s, (float*)d_out);
}

// Round 7
// 108.138 us; speedup vs baseline: 1.4528x; 1.4528x over previous
//
#include <hip/hip_runtime.h>
#include <hip/hip_bf16.h>
#include <math.h>

// Problem constants (fixed by setup_inputs)
#define NX 192
#define NY 192
#define NPIX (NX * NY)     // 36864
#define ETLN 16
#define DATOMS 4000
#define SCH 10             // atom chunks (grid.y)
#define CHUNK 400          // atoms per chunk (25 tiles, odd -> 12 pairs + 1)
#define CHB (CHUNK * 64)   // chunk bytes = 25600
#define PXB (NPIX / 128)   // 288 pixel blocks (128 px/block, 32 px/wave)

typedef __attribute__((ext_vector_type(8))) short short8;
typedef __attribute__((ext_vector_type(4))) float f32x4;
typedef unsigned short ushort;
typedef unsigned int uint;
typedef unsigned long long u64;

// ---- ws layout (bytes) ----
// A1   : 4000*64 = 256000   atom rows, TILE-SLICE-MAJOR layout per chunk:
//                           [chunk][tile][slice s=0..3][row r=0..15] x 16B
// PART : SCH*NPIX*8 = 2949120  per-(chunk,px) u64 keys, plain stores
#define OFF_A1   0
#define OFF_PART 256000

// R14: fusing finalize into match regressed -> keep separate.
// R17 FAILED: XOR-swizzled LDS (unverified algebra).
// R19: conflict-free tile-slice-major staging: conflicts -9x but only -2us
// (44->42). Interior of the loop is not the constraint (latency-bound:
// MfmaUtil 16%, VALUBusy 45%, Occupancy 24%, LDS-capped 3 blocks/CU).
// R20 FAILED the occupancy test: __launch_bounds__(256,6) forced VGPR cap
// ~85 -> allocator collapsed to VGPR 40 + 300MB scratch spill traffic
// (WRITE_SIZE 3.4MB->192MB), 42->91us. CHUNK=400 data path itself passed
// (absmax 0.00098) -- odd tail + 10-chunk finalize are verified.
// R21 (this round): SAME kernel, launch_bounds (256,4): VGPR cap 128 ->
// compiler returns to natural ~84 regs (no spill); LDS 25.6KB x4 = 102KB
// -> 4 blocks/CU = 16 waves/CU resident (+33% vs R19's 12). Clean
// occupancy experiment, one variable.

__device__ __forceinline__ int mask_and_z(const float* __restrict__ delta_ms,
                                          float* mask) {
    int z = -1;
#pragma unroll
    for (int e = 0; e < ETLN; ++e) {
        float m = (delta_ms[e] * 1e-3f < 1e-3f) ? 1.0f : 0.0f;
        mask[e] = m;
        if (m == 0.0f && z < 0) z = e;
    }
    return z;
}

// bf16 split: returns bf16 bits of x (RN); *rem = x - float(bf16(x)) (exact)
__device__ __forceinline__ ushort bfsplit(float x, float* rem) {
    __hip_bfloat16 h = __float2bfloat16(x);
    *rem = x - __bfloat162float(h);
    union { __hip_bfloat16 h; ushort u; } cv;
    cv.h = h;
    return cv.u;
}

// Two-stage normalize -> t = -2*s, sentinel t[z]=1 via SELECT (R4 lesson:
// no dynamic-index alloca stores). Reciprocal-mul: 2 divides total.
__device__ __forceinline__ void compute_t(const float* __restrict__ row,
                                          const float* mask, int z,
                                          float* tv, float* s2out) {
    float x[ETLN];
    const float4* r4 = (const float4*)row;
#pragma unroll
    for (int q = 0; q < 4; ++q) {
        float4 a = r4[q];
        x[4 * q + 0] = a.x; x[4 * q + 1] = a.y;
        x[4 * q + 2] = a.z; x[4 * q + 3] = a.w;
    }
    float n1s = 0.f;
#pragma unroll
    for (int e = 0; e < ETLN; ++e) n1s += x[e] * x[e];
    float n1 = sqrtf(n1s);
    float inv1 = (n1 > 0.f) ? (1.0f / n1) : 0.f;
#pragma unroll
    for (int e = 0; e < ETLN; ++e) x[e] = x[e] * inv1 * mask[e];
    float n2s = 0.f;
#pragma unroll
    for (int e = 0; e < ETLN; ++e) n2s += x[e] * x[e];
    float n2 = sqrtf(n2s);
    float inv2 = (n2 > 0.f) ? (1.0f / n2) : 0.f;
    float s2 = 0.f;
#pragma unroll
    for (int e = 0; e < ETLN; ++e) {
        float y = x[e] * inv2;
        s2 += y * y;
        float t = -2.0f * y;
        tv[e] = (e == z) ? 1.0f : t;
    }
    *s2out = s2;
}

// atom row: mask -> normalize -> d2 in sentinel col (exact prep semantics)
__device__ __forceinline__ void atom_row(const float* __restrict__ row,
                                         const float* mask, int z, float* w) {
    float v[ETLN];
    const float4* q4 = (const float4*)row;
#pragma unroll
    for (int q = 0; q < 4; ++q) {
        float4 a = q4[q];
        v[4 * q + 0] = a.x * mask[4 * q + 0];
        v[4 * q + 1] = a.y * mask[4 * q + 1];
        v[4 * q + 2] = a.z * mask[4 * q + 2];
        v[4 * q + 3] = a.w * mask[4 * q + 3];
    }
    float ss = 0.f;
#pragma unroll
    for (int e = 0; e < ETLN; ++e) ss += v[e] * v[e];
    float n = sqrtf(ss);
    float inv = (n > 0.f) ? (1.0f / n) : 0.f;
    float d2 = 0.f;
#pragma unroll
    for (int e = 0; e < ETLN; ++e) {
        float y = v[e] * inv;
        v[e] = y;
        d2 += y * y;
    }
#pragma unroll
    for (int e = 0; e < ETLN; ++e) w[e] = (e == z) ? d2 : v[e];
}

// bf16 2-way split row -> 16 packed dwords, slice order:
// fd[0..3]=Ah[0:8] fd[4..7]=Ah[8:16] fd[8..11]=Am[0:8] fd[12..15]=Am[8:16]
__device__ __forceinline__ void pack_row16(const float* w, uint* fd) {
    uint hb[ETLN], mb[ETLN];
#pragma unroll
    for (int e = 0; e < ETLN; ++e) {
        float r1, dmy;
        hb[e] = (uint)bfsplit(w[e], &r1);
        mb[e] = (uint)bfsplit(r1, &dmy);
    }
#pragma unroll
    for (int k = 0; k < 4; ++k) {
        fd[k]      = hb[2 * k]     | (hb[2 * k + 1] << 16);
        fd[4 + k]  = hb[8 + 2 * k] | (hb[9 + 2 * k] << 16);
        fd[8 + k]  = mb[2 * k]     | (mb[2 * k + 1] << 16);
        fd[12 + k] = mb[8 + 2 * k] | (mb[8 + 2 * k + 1] << 16);
    }
}

// prep_atoms: 4000 threads -> A1 in tile-slice-major layout (~1-2us)
__global__ __launch_bounds__(256) void prep_atoms(
        const float* __restrict__ db_mag, const float* __restrict__ delta_ms,
        char* __restrict__ A1) {
    int t = blockIdx.x * 256 + threadIdx.x;
    if (t >= DATOMS) return;
    float mask[ETLN];
    int z = mask_and_z(delta_ms, mask);
    float w[ETLN];
    atom_row(db_mag + (size_t)t * ETLN, mask, z, w);
    uint fd[16];
    pack_row16(w, fd);
    int chunk = t / CHUNK, jj = t % CHUNK;
    int tile = jj >> 4, row = jj & 15;
    char* base = A1 + (size_t)chunk * CHB + tile * 1024 + row * 16;
#pragma unroll
    for (int s = 0; s < 4; ++s)
        *(uint4*)(base + s * 256) = make_uint4(fd[4 * s], fd[4 * s + 1],
                                               fd[4 * s + 2], fd[4 * s + 3]);
}

// identity 64B row store (4x b128) -- pixel scratch only
__device__ __forceinline__ void store_row16(char* rowbase, const uint* fd) {
#pragma unroll
    for (int s = 0; s < 4; ++s) {
        ((uint4*)rowbase)[s] = make_uint4(fd[4 * s], fd[4 * s + 1],
                                          fd[4 * s + 2], fd[4 * s + 3]);
    }
}

// Approx filter key (R16-verified): single v_and_or_b32 key, octet-min.
__device__ __forceinline__ void top2_update8(f32x4 aLo, f32x4 aHi,
                                             uint i0, uint i1, uint i2, uint i3,
                                             uint* k1, uint* k2) {
    uint kk0 = (__float_as_uint(aLo[0]) & 0xFFFFF000u) | i0;
    uint kk1 = (__float_as_uint(aLo[1]) & 0xFFFFF000u) | i1;
    uint kk2 = (__float_as_uint(aLo[2]) & 0xFFFFF000u) | i2;
    uint kk3 = (__float_as_uint(aLo[3]) & 0xFFFFF000u) | i3;
    uint kk4 = (__float_as_uint(aHi[0]) & 0xFFFFF000u) | (i0 + 16u);
    uint kk5 = (__float_as_uint(aHi[1]) & 0xFFFFF000u) | (i1 + 16u);
    uint kk6 = (__float_as_uint(aHi[2]) & 0xFFFFF000u) | (i2 + 16u);
    uint kk7 = (__float_as_uint(aHi[3]) & 0xFFFFF000u) | (i3 + 16u);
    uint t = min(min(min(kk0, kk1), min(kk2, kk3)),
                 min(min(kk4, kk5), min(kk6, kk7)));
    bool lt = t < *k1;
    uint mn2 = min(*k2, t);
    *k2 = lt ? *k1 : mn2;
    *k1 = min(*k1, t);
}

// 4-value variant for the odd single-tile tail (quartet-min candidate).
__device__ __forceinline__ void top2_update4(f32x4 a, uint i0, uint i1,
                                             uint i2, uint i3,
                                             uint* k1, uint* k2) {
    uint kk0 = (__float_as_uint(a[0]) & 0xFFFFF000u) | i0;
    uint kk1 = (__float_as_uint(a[1]) & 0xFFFFF000u) | i1;
    uint kk2 = (__float_as_uint(a[2]) & 0xFFFFF000u) | i2;
    uint kk3 = (__float_as_uint(a[3]) & 0xFFFFF000u) | i3;
    uint t = min(min(kk0, kk1), min(kk2, kk3));
    bool lt = t < *k1;
    uint mn2 = min(*k2, t);
    *k2 = lt ? *k1 : mn2;
    *k1 = min(*k1, t);
}

// Score one 2-tile pair (32 atoms x 32 pixels): 8 MFMA + 2 top2_update8.
__device__ __forceinline__ void proc_pair(
        short8 t0, short8 t1, short8 V1A, short8 V2A, short8 V1B, short8 V2B,
        f32x4 cinit, uint i0, uint i1, uint i2, uint i3,
        uint* k1A, uint* k2A, uint* k1B, uint* k2B) {
    f32x4 a00 = __builtin_amdgcn_mfma_f32_16x16x32_bf16(t0, V1A, cinit, 0, 0, 0);
    f32x4 a01 = __builtin_amdgcn_mfma_f32_16x16x32_bf16(t0, V1B, cinit, 0, 0, 0);
    f32x4 a10 = __builtin_amdgcn_mfma_f32_16x16x32_bf16(t1, V1A, cinit, 0, 0, 0);
    f32x4 a11 = __builtin_amdgcn_mfma_f32_16x16x32_bf16(t1, V1B, cinit, 0, 0, 0);
    a00 = __builtin_amdgcn_mfma_f32_16x16x32_bf16(t0, V2A, a00, 0, 0, 0);
    a01 = __builtin_amdgcn_mfma_f32_16x16x32_bf16(t0, V2B, a01, 0, 0, 0);
    a10 = __builtin_amdgcn_mfma_f32_16x16x32_bf16(t1, V2A, a10, 0, 0, 0);
    a11 = __builtin_amdgcn_mfma_f32_16x16x32_bf16(t1, V2B, a11, 0, 0, 0);
    asm("" : "+v"(a00), "+v"(a01), "+v"(a10), "+v"(a11));
    top2_update8(a00, a10, i0, i1, i2, i3, k1A, k2A);   // pixel set A
    top2_update8(a01, a11, i0, i1, i2, i3, k1B, k2B);   // pixel set B
}

// Score one single tile (16 atoms x 32 px): 4 MFMA + 2 top2_update4.
__device__ __forceinline__ void proc_single(
        short8 t0, short8 V1A, short8 V2A, short8 V1B, short8 V2B,
        f32x4 cinit, uint i0, uint i1, uint i2, uint i3,
        uint* k1A, uint* k2A, uint* k1B, uint* k2B) {
    f32x4 a00 = __builtin_amdgcn_mfma_f32_16x16x32_bf16(t0, V1A, cinit, 0, 0, 0);
    f32x4 a01 = __builtin_amdgcn_mfma_f32_16x16x32_bf16(t0, V1B, cinit, 0, 0, 0);
    a00 = __builtin_amdgcn_mfma_f32_16x16x32_bf16(t0, V2A, a00, 0, 0, 0);
    a01 = __builtin_amdgcn_mfma_f32_16x16x32_bf16(t0, V2B, a01, 0, 0, 0);
    asm("" : "+v"(a00), "+v"(a01));
    top2_update4(a00, i0, i1, i2, i3, k1A, k2A);
    top2_update4(a01, i0, i1, i2, i3, k1B, k2B);
}

// Monotone total-order map for signed f32 (R9-verified selection semantics).
__device__ __forceinline__ uint fmono(float f) {
    uint b = __float_as_uint(f);
    return b ^ (uint)(((int)b >> 31) | 0x80000000);
}

// match_fused: pixel frags in-wave via LDS scratch (first 8KB, identity
// layout); atom chunk copied A1->LDS (coalesced uint4 + contiguous
// ds_write_b128); main loop reads tiles at quad*256 + l15*16 (contiguous
// 1KB/wave-tile, conflict-free); ping-pong pipeline; epilogue rescores
// exact atoms from db_mag; plain store to partial[chunk][px].
// R21: launch_bounds (256,4) -- VGPR cap 128 (natural ~84, no spill),
// LDS 25.6KB -> 4 blocks/CU = 16 waves/CU resident.
__global__ __launch_bounds__(256, 4) void match_fused(
        const float* __restrict__ sig, const float* __restrict__ db_mag,
        const float* __restrict__ delta_ms, const char* __restrict__ A1,
        u64* __restrict__ partial) {
    __shared__ __align__(1024) char smem[CHB];   // 25600 B

    const int lane = threadIdx.x & 63;
    const int wv   = threadIdx.x >> 6;
    const int quad = lane >> 4;
    const int l15  = lane & 15;
    const int pl   = lane & 31;

    float mask[ETLN];
    int z = mask_and_z(delta_ms, mask);

    // ---- pixel phase: all lanes compute pixel wbase+(lane&31) ----
    const int wbase = blockIdx.x * 128 + wv * 32;
    float tv[ETLN], s2px;
    compute_t(sig + (size_t)(wbase + pl) * ETLN, mask, z, tv, &s2px);
    {
        uint fd[16];
        pack_row16(tv, fd);
        if (lane < 32) store_row16(smem + wv * 2048 + pl * 64, fd);
    }
    __syncthreads();

    // V1 = slice[quad] at quad*16; V2 = slice[quad^2] (R18-verified offsets)
    const char* pb = smem + wv * 2048 + l15 * 64;
    short8 V1A = *(const short8*)(pb + quad * 16);
    short8 V2A = *(const short8*)(pb + (quad ^ 2) * 16);
    short8 V1B = *(const short8*)(pb + 1024 + quad * 16);
    short8 V2B = *(const short8*)(pb + 1024 + (quad ^ 2) * 16);
    asm("" : "+v"(V1A), "+v"(V2A), "+v"(V1B), "+v"(V2B));
    __syncthreads();   // frag reads drained before copy overwrites scratch

    // ---- atom stage: plain copy A1 chunk -> LDS (layout already final) ----
    const char* src = A1 + (size_t)blockIdx.y * CHB;
    for (int r = 0; r < 7; ++r) {
        int c = (int)threadIdx.x + r * 256;
        if (c < CHB / 16) {
            uint4 v = *(const uint4*)(src + (size_t)c * 16);
            *(uint4*)(smem + (size_t)c * 16) = v;
        }
    }
    __syncthreads();

    // ---- main loop: ping-pong; conflict-free reads (contiguous 1KB) ----
    // CT=25 tiles: prime 4 + 5 iters (4 tiles each) + 2 tail pairs + single
    uint k1A = 0xFFFFFFFFu, k2A = 0xFFFFFFFFu;
    uint k1B = 0xFFFFFFFFu, k2B = 0xFFFFFFFFu;
    const f32x4 cinit = (f32x4){1.0f, 1.0f, 1.0f, 1.0f};   // f' = dist^2

    const int jbase = blockIdx.y * CHUNK;
    const char* abase = smem + quad * 256 + l15 * 16;
    uint i0 = (uint)(jbase + quad * 4);
    uint i1 = i0 + 1u, i2 = i0 + 2u, i3 = i0 + 3u;

    short8 x0 = *(const short8*)(abase);
    short8 x1 = *(const short8*)(abase + 1024);
    short8 y0 = *(const short8*)(abase + 2048);
    short8 y1 = *(const short8*)(abase + 3072);
    const char* W = abase + 4096;

#pragma unroll 1
    for (int it = 0; it < 5; ++it) {
        asm("" : "+v"(x0), "+v"(x1));
        proc_pair(x0, x1, V1A, V2A, V1B, V2B, cinit, i0, i1, i2, i3,
                  &k1A, &k2A, &k1B, &k2B);
        i0 += 32u; i1 += 32u; i2 += 32u; i3 += 32u;
        x0 = *(const short8*)(W);            // tiles 4it+4, 4it+5
        x1 = *(const short8*)(W + 1024);
        asm("" : "+v"(y0), "+v"(y1));
        proc_pair(y0, y1, V1A, V2A, V1B, V2B, cinit, i0, i1, i2, i3,
                  &k1A, &k2A, &k1B, &k2B);
        i0 += 32u; i1 += 32u; i2 += 32u; i3 += 32u;
        y0 = *(const short8*)(W + 2048);     // tiles 4it+6, 4it+7
        y1 = *(const short8*)(W + 3072);
        W += 4096;
    }
    // tail: x = tiles 20,21; y = 22,23; W -> tile 24
    proc_pair(x0, x1, V1A, V2A, V1B, V2B, cinit, i0, i1, i2, i3,
              &k1A, &k2A, &k1B, &k2B);
    i0 += 32u; i1 += 32u; i2 += 32u; i3 += 32u;
    proc_pair(y0, y1, V1A, V2A, V1B, V2B, cinit, i0, i1, i2, i3,
              &k1A, &k2A, &k1B, &k2B);
    i0 += 32u; i1 += 32u; i2 += 32u; i3 += 32u;
    short8 z0 = *(const short8*)(W);
    proc_single(z0, V1A, V2A, V1B, V2B, cinit, i0, i1, i2, i3,
                &k1A, &k2A, &k1B, &k2B);

    // ---- epilogue: cross-quad top-2 merge, EXACT rescore from db_mag ----
    float tvB[ETLN], s2B;
#pragma unroll
    for (int e = 0; e < ETLN; ++e) tvB[e] = __shfl(tv[e], lane + 16);
    s2B = __shfl(s2px, lane + 16);

#pragma unroll
    for (int g = 0; g < 2; ++g) {
        uint p1 = g ? k1B : k1A;
        uint p2 = g ? k2B : k2A;
#pragma unroll
        for (int off = 16; off <= 32; off <<= 1) {
            uint o1 = (uint)__shfl_xor((int)p1, off);
            uint o2 = (uint)__shfl_xor((int)p2, off);
            uint n1 = p1 < o1 ? p1 : o1;
            uint mx = p1 < o1 ? o1 : p1;
            uint mn = p2 < o2 ? p2 : o2;
            p2 = mx < mn ? mx : mn;
            p1 = n1;
        }
        if (lane < 16) {
            int px = wbase + lane + (g ? 16 : 0);
            int j1 = (int)(p1 & 0xFFFu);
            int j2 = (int)(p2 & 0xFFFu);
            const float* tvx = g ? tvB : tv;
            float sx = g ? s2B : s2px;
            float w1[ETLN], w2[ETLN];
            atom_row(db_mag + (size_t)j1 * ETLN, mask, z, w1);
            atom_row(db_mag + (size_t)j2 * ETLN, mask, z, w2);
            float f1 = 0.f, f2 = 0.f;
#pragma unroll
            for (int e = 0; e < ETLN; ++e) {
                f1 = fmaf(w1[e], tvx[e], f1);
                f2 = fmaf(w2[e], tvx[e], f2);
            }
            u64 key1 = (((u64)fmono(f1 + sx)) << 32) | (uint)j1;
            u64 key2 = (((u64)fmono(f2 + sx)) << 32) | (uint)j2;
            partial[(size_t)blockIdx.y * NPIX + px] =
                key1 < key2 ? key1 : key2;
        }
    }
}

// finalize: min over 10 chunk keys, decode (monotone bits of f+s2, j)
__global__ __launch_bounds__(256) void finalize(
        const u64* __restrict__ partial, const float* __restrict__ t2s,
        const float* __restrict__ b1s, float* __restrict__ out) {
    int p = blockIdx.x * 256 + threadIdx.x;
    if (p >= NPIX) return;
    u64 m = partial[p];
#pragma unroll
    for (int c = 1; c < SCH; ++c) {
        u64 v = partial[(size_t)c * NPIX + p];
        m = v < m ? v : m;
    }
    int j = (int)(m & 0xFFFu);
    uint mb = (uint)(m >> 32);
    uint b = (mb & 0x80000000u) ? (mb ^ 0x80000000u) : ~mb;  // fmono^-1
    float val = __uint_as_float(b);                          // = f + s2
    out[p] = t2s[j];
    out[NPIX + p] = b1s[j];
    out[2 * NPIX + p] = sqrtf(fmaxf(val, 0.0f));
}

extern "C" void kernel_launch(void* const* d_in, const int* in_sizes, int n_in,
                              void* d_out, int out_size, void* d_ws, size_t ws_size,
                              hipStream_t stream) {
    const float* sig    = (const float*)d_in[0];  // [192,192,16]
    const float* db_mag = (const float*)d_in[1];  // [4000,16]
    const float* t2s    = (const float*)d_in[2];  // [4000]
    const float* b1s    = (const float*)d_in[3];  // [4000]
    const float* delta  = (const float*)d_in[4];  // [16]

    char* ws = (char*)d_ws;
    char* A1      = ws + OFF_A1;
    u64*  partial = (u64*)(ws + OFF_PART);

    prep_atoms<<<(DATOMS + 255) / 256, 256, 0, stream>>>(db_mag, delta, A1);
    dim3 grid(PXB, SCH);
    match_fused<<<grid, 256, 0, stream>>>(sig, db_mag, delta, A1, partial);
    finalize<<<PXB / 2, 256, 0, stream>>>(partial, t2s, b1s, (float*)d_out);
}

// Round 8
// 96.150 us; speedup vs baseline: 1.6340x; 1.1247x over previous
//
#include <hip/hip_runtime.h>
#include <hip/hip_bf16.h>
#include <math.h>

// Problem constants (fixed by setup_inputs)
#define NX 192
#define NY 192
#define NPIX (NX * NY)     // 36864
#define ETLN 16
#define DATOMS 4000
#define SCH 5              // atom chunks (grid.y)
#define CHUNK 800          // atoms per chunk (50 tiles = 25 pairs)
#define CHB (CHUNK * 64)   // chunk bytes = 51200
#define PXB (NPIX / 128)   // 288 pixel blocks (128 px/block, 32 px/wave)

typedef __attribute__((ext_vector_type(8))) short short8;
typedef __attribute__((ext_vector_type(4))) float f32x4;
typedef unsigned short ushort;
typedef unsigned int uint;
typedef unsigned long long u64;

// ---- ws layout (bytes) ----
// A1   : 4000*64 = 256000   atom rows, TILE-SLICE-MAJOR layout per chunk:
//                           [chunk][tile][slice s=0..3][row r=0..15] x 16B
// PART : SCH*NPIX*8 = 1474560  per-(chunk,px) u64 keys, plain stores
#define OFF_A1   0
#define OFF_PART 256000

// SESSION MODEL (R4-R7 fit): total ~= match + ~56us fixed. match is the
// only lever that passes through to dur_us.
// R17 FAILED: XOR-swizzle. R19 (best): conflict-free staging, 42.2us match,
// MfmaUtil 16 / VALUBusy 45 / Occ 24 -- latency-bound, not issue-bound
// (instruction floor ~5-9us). R20/R21 FAILED occupancy: any VGPR cap below
// the natural ~84 -> allocator cliff (VGPR 40/64) + scratch spills
// (WRITE 3.4MB -> 192/20MB), match 91/51us. Occupancy lever is exhausted.
// R22 (this round): keep R19 config byte-for-byte; SOFTWARE-PIPELINE the
// top2 one pair behind the MFMAs (two named pending acc sets e*/o*, manual
// 2-stage rotation, static indexing). Every MFMA group gets ~100cyc of
// independent work between write and consume, in both loop phases.

__device__ __forceinline__ int mask_and_z(const float* __restrict__ delta_ms,
                                          float* mask) {
    int z = -1;
#pragma unroll
    for (int e = 0; e < ETLN; ++e) {
        float m = (delta_ms[e] * 1e-3f < 1e-3f) ? 1.0f : 0.0f;
        mask[e] = m;
        if (m == 0.0f && z < 0) z = e;
    }
    return z;
}

// bf16 split: returns bf16 bits of x (RN); *rem = x - float(bf16(x)) (exact)
__device__ __forceinline__ ushort bfsplit(float x, float* rem) {
    __hip_bfloat16 h = __float2bfloat16(x);
    *rem = x - __bfloat162float(h);
    union { __hip_bfloat16 h; ushort u; } cv;
    cv.h = h;
    return cv.u;
}

// Two-stage normalize -> t = -2*s, sentinel t[z]=1 via SELECT (R4 lesson:
// no dynamic-index alloca stores). Reciprocal-mul: 2 divides total.
__device__ __forceinline__ void compute_t(const float* __restrict__ row,
                                          const float* mask, int z,
                                          float* tv, float* s2out) {
    float x[ETLN];
    const float4* r4 = (const float4*)row;
#pragma unroll
    for (int q = 0; q < 4; ++q) {
        float4 a = r4[q];
        x[4 * q + 0] = a.x; x[4 * q + 1] = a.y;
        x[4 * q + 2] = a.z; x[4 * q + 3] = a.w;
    }
    float n1s = 0.f;
#pragma unroll
    for (int e = 0; e < ETLN; ++e) n1s += x[e] * x[e];
    float n1 = sqrtf(n1s);
    float inv1 = (n1 > 0.f) ? (1.0f / n1) : 0.f;
#pragma unroll
    for (int e = 0; e < ETLN; ++e) x[e] = x[e] * inv1 * mask[e];
    float n2s = 0.f;
#pragma unroll
    for (int e = 0; e < ETLN; ++e) n2s += x[e] * x[e];
    float n2 = sqrtf(n2s);
    float inv2 = (n2 > 0.f) ? (1.0f / n2) : 0.f;
    float s2 = 0.f;
#pragma unroll
    for (int e = 0; e < ETLN; ++e) {
        float y = x[e] * inv2;
        s2 += y * y;
        float t = -2.0f * y;
        tv[e] = (e == z) ? 1.0f : t;
    }
    *s2out = s2;
}

// atom row: mask -> normalize -> d2 in sentinel col (exact prep semantics)
__device__ __forceinline__ void atom_row(const float* __restrict__ row,
                                         const float* mask, int z, float* w) {
    float v[ETLN];
    const float4* q4 = (const float4*)row;
#pragma unroll
    for (int q = 0; q < 4; ++q) {
        float4 a = q4[q];
        v[4 * q + 0] = a.x * mask[4 * q + 0];
        v[4 * q + 1] = a.y * mask[4 * q + 1];
        v[4 * q + 2] = a.z * mask[4 * q + 2];
        v[4 * q + 3] = a.w * mask[4 * q + 3];
    }
    float ss = 0.f;
#pragma unroll
    for (int e = 0; e < ETLN; ++e) ss += v[e] * v[e];
    float n = sqrtf(ss);
    float inv = (n > 0.f) ? (1.0f / n) : 0.f;
    float d2 = 0.f;
#pragma unroll
    for (int e = 0; e < ETLN; ++e) {
        float y = v[e] * inv;
        v[e] = y;
        d2 += y * y;
    }
#pragma unroll
    for (int e = 0; e < ETLN; ++e) w[e] = (e == z) ? d2 : v[e];
}

// bf16 2-way split row -> 16 packed dwords, slice order:
// fd[0..3]=Ah[0:8] fd[4..7]=Ah[8:16] fd[8..11]=Am[0:8] fd[12..15]=Am[8:16]
__device__ __forceinline__ void pack_row16(const float* w, uint* fd) {
    uint hb[ETLN], mb[ETLN];
#pragma unroll
    for (int e = 0; e < ETLN; ++e) {
        float r1, dmy;
        hb[e] = (uint)bfsplit(w[e], &r1);
        mb[e] = (uint)bfsplit(r1, &dmy);
    }
#pragma unroll
    for (int k = 0; k < 4; ++k) {
        fd[k]      = hb[2 * k]     | (hb[2 * k + 1] << 16);
        fd[4 + k]  = hb[8 + 2 * k] | (hb[9 + 2 * k] << 16);
        fd[8 + k]  = mb[2 * k]     | (mb[2 * k + 1] << 16);
        fd[12 + k] = mb[8 + 2 * k] | (mb[8 + 2 * k + 1] << 16);
    }
}

// prep_atoms: 4000 threads -> A1 in tile-slice-major layout (~1-2us)
__global__ __launch_bounds__(256) void prep_atoms(
        const float* __restrict__ db_mag, const float* __restrict__ delta_ms,
        char* __restrict__ A1) {
    int t = blockIdx.x * 256 + threadIdx.x;
    if (t >= DATOMS) return;
    float mask[ETLN];
    int z = mask_and_z(delta_ms, mask);
    float w[ETLN];
    atom_row(db_mag + (size_t)t * ETLN, mask, z, w);
    uint fd[16];
    pack_row16(w, fd);
    int chunk = t / CHUNK, jj = t % CHUNK;
    int tile = jj >> 4, row = jj & 15;
    char* base = A1 + (size_t)chunk * CHB + tile * 1024 + row * 16;
#pragma unroll
    for (int s = 0; s < 4; ++s)
        *(uint4*)(base + s * 256) = make_uint4(fd[4 * s], fd[4 * s + 1],
                                               fd[4 * s + 2], fd[4 * s + 3]);
}

// identity 64B row store (4x b128) -- pixel scratch only
__device__ __forceinline__ void store_row16(char* rowbase, const uint* fd) {
#pragma unroll
    for (int s = 0; s < 4; ++s) {
        ((uint4*)rowbase)[s] = make_uint4(fd[4 * s], fd[4 * s + 1],
                                          fd[4 * s + 2], fd[4 * s + 3]);
    }
}

// Approx filter key (R16-verified): single v_and_or_b32 key, octet-min.
__device__ __forceinline__ void top2_update8(f32x4 aLo, f32x4 aHi,
                                             uint i0, uint i1, uint i2, uint i3,
                                             uint* k1, uint* k2) {
    uint kk0 = (__float_as_uint(aLo[0]) & 0xFFFFF000u) | i0;
    uint kk1 = (__float_as_uint(aLo[1]) & 0xFFFFF000u) | i1;
    uint kk2 = (__float_as_uint(aLo[2]) & 0xFFFFF000u) | i2;
    uint kk3 = (__float_as_uint(aLo[3]) & 0xFFFFF000u) | i3;
    uint kk4 = (__float_as_uint(aHi[0]) & 0xFFFFF000u) | (i0 + 16u);
    uint kk5 = (__float_as_uint(aHi[1]) & 0xFFFFF000u) | (i1 + 16u);
    uint kk6 = (__float_as_uint(aHi[2]) & 0xFFFFF000u) | (i2 + 16u);
    uint kk7 = (__float_as_uint(aHi[3]) & 0xFFFFF000u) | (i3 + 16u);
    uint t = min(min(min(kk0, kk1), min(kk2, kk3)),
                 min(min(kk4, kk5), min(kk6, kk7)));
    bool lt = t < *k1;
    uint mn2 = min(*k2, t);
    *k2 = lt ? *k1 : mn2;
    *k1 = min(*k1, t);
}

// Issue the 8 MFMAs for one 2-tile pair (32 atoms x 32 px). Barrier pins
// the accs so the compiler cannot sink the MFMAs to their (deferred) use.
__device__ __forceinline__ void mfma8(
        short8 t0, short8 t1, short8 V1A, short8 V2A, short8 V1B, short8 V2B,
        f32x4 cinit, f32x4* a00, f32x4* a01, f32x4* a10, f32x4* a11) {
    f32x4 b00 = __builtin_amdgcn_mfma_f32_16x16x32_bf16(t0, V1A, cinit, 0, 0, 0);
    f32x4 b01 = __builtin_amdgcn_mfma_f32_16x16x32_bf16(t0, V1B, cinit, 0, 0, 0);
    f32x4 b10 = __builtin_amdgcn_mfma_f32_16x16x32_bf16(t1, V1A, cinit, 0, 0, 0);
    f32x4 b11 = __builtin_amdgcn_mfma_f32_16x16x32_bf16(t1, V1B, cinit, 0, 0, 0);
    b00 = __builtin_amdgcn_mfma_f32_16x16x32_bf16(t0, V2A, b00, 0, 0, 0);
    b01 = __builtin_amdgcn_mfma_f32_16x16x32_bf16(t0, V2B, b01, 0, 0, 0);
    b10 = __builtin_amdgcn_mfma_f32_16x16x32_bf16(t1, V2A, b10, 0, 0, 0);
    b11 = __builtin_amdgcn_mfma_f32_16x16x32_bf16(t1, V2B, b11, 0, 0, 0);
    asm("" : "+v"(b00), "+v"(b01), "+v"(b10), "+v"(b11));
    *a00 = b00; *a01 = b01; *a10 = b10; *a11 = b11;
}

// Deferred top2 consumption of one pair's accs.
__device__ __forceinline__ void top2_pair(
        f32x4 a00, f32x4 a01, f32x4 a10, f32x4 a11,
        uint i0, uint i1, uint i2, uint i3,
        uint* k1A, uint* k2A, uint* k1B, uint* k2B) {
    top2_update8(a00, a10, i0, i1, i2, i3, k1A, k2A);   // pixel set A
    top2_update8(a01, a11, i0, i1, i2, i3, k1B, k2B);   // pixel set B
}

// Monotone total-order map for signed f32 (R9-verified selection semantics).
__device__ __forceinline__ uint fmono(float f) {
    uint b = __float_as_uint(f);
    return b ^ (uint)(((int)b >> 31) | 0x80000000);
}

// match_fused: R19 data path (pixel frags in-wave via LDS scratch; chunk
// copied A1->LDS; conflict-free tile reads at quad*256+l15*16; exact
// rescore from db_mag; plain partial stores). R22: software-pipelined
// main loop -- top2 runs one pair behind the MFMAs via e*/o* pending sets.
__global__ __launch_bounds__(256, 3) void match_fused(
        const float* __restrict__ sig, const float* __restrict__ db_mag,
        const float* __restrict__ delta_ms, const char* __restrict__ A1,
        u64* __restrict__ partial) {
    __shared__ __align__(1024) char smem[CHB];   // 51200 B

    const int lane = threadIdx.x & 63;
    const int wv   = threadIdx.x >> 6;
    const int quad = lane >> 4;
    const int l15  = lane & 15;
    const int pl   = lane & 31;

    float mask[ETLN];
    int z = mask_and_z(delta_ms, mask);

    // ---- pixel phase: all lanes compute pixel wbase+(lane&31) ----
    const int wbase = blockIdx.x * 128 + wv * 32;
    float tv[ETLN], s2px;
    compute_t(sig + (size_t)(wbase + pl) * ETLN, mask, z, tv, &s2px);
    {
        uint fd[16];
        pack_row16(tv, fd);
        if (lane < 32) store_row16(smem + wv * 2048 + pl * 64, fd);
    }
    __syncthreads();

    // V1 = slice[quad] at quad*16; V2 = slice[quad^2] (R18-verified offsets)
    const char* pb = smem + wv * 2048 + l15 * 64;
    short8 V1A = *(const short8*)(pb + quad * 16);
    short8 V2A = *(const short8*)(pb + (quad ^ 2) * 16);
    short8 V1B = *(const short8*)(pb + 1024 + quad * 16);
    short8 V2B = *(const short8*)(pb + 1024 + (quad ^ 2) * 16);
    asm("" : "+v"(V1A), "+v"(V2A), "+v"(V1B), "+v"(V2B));
    __syncthreads();   // frag reads drained before copy overwrites scratch

    // ---- atom stage: plain copy A1 chunk -> LDS (layout already final) ----
    const char* src = A1 + (size_t)blockIdx.y * CHB;
    for (int r = 0; r < 13; ++r) {
        int c = (int)threadIdx.x + r * 256;
        if (c < CHB / 16) {
            uint4 v = *(const uint4*)(src + (size_t)c * 16);
            *(uint4*)(smem + (size_t)c * 16) = v;
        }
    }
    __syncthreads();

    // ---- main loop: pipelined; 25 pairs (50 tiles), conflict-free reads --
    uint k1A = 0xFFFFFFFFu, k2A = 0xFFFFFFFFu;
    uint k1B = 0xFFFFFFFFu, k2B = 0xFFFFFFFFu;
    const f32x4 cinit = (f32x4){1.0f, 1.0f, 1.0f, 1.0f};   // f' = dist^2

    const int jbase = blockIdx.y * CHUNK;
    const char* abase = smem + quad * 256 + l15 * 16;
    uint i0 = (uint)(jbase + quad * 4);
    uint i1 = i0 + 1u, i2 = i0 + 2u, i3 = i0 + 3u;

    short8 x0 = *(const short8*)(abase);           // pair0: tiles 0,1
    short8 x1 = *(const short8*)(abase + 1024);
    short8 y0 = *(const short8*)(abase + 2048);    // pair1: tiles 2,3
    short8 y1 = *(const short8*)(abase + 3072);

    f32x4 e00, e01, e10, e11;    // pending even-pair accs
    f32x4 o00, o01, o10, o11;    // pending odd-pair accs
    uint iE0, iE1, iE2, iE3, iO0, iO1, iO2, iO3;

    // prime: MFMA pair0 (x); its top2 is deferred to the first loop iter
    asm("" : "+v"(x0), "+v"(x1));
    mfma8(x0, x1, V1A, V2A, V1B, V2B, cinit, &e00, &e01, &e10, &e11);
    iE0 = i0; iE1 = i1; iE2 = i2; iE3 = i3;
    i0 += 32u; i1 += 32u; i2 += 32u; i3 += 32u;
    x0 = *(const short8*)(abase + 4096);           // pair2: tiles 4,5
    x1 = *(const short8*)(abase + 5120);
    const char* W = abase + 6144;

#pragma unroll 1
    for (int it = 0; it < 11; ++it) {
        // MFMA pair 2it+1 (y), then consume pair 2it (pending e)
        asm("" : "+v"(y0), "+v"(y1));
        mfma8(y0, y1, V1A, V2A, V1B, V2B, cinit, &o00, &o01, &o10, &o11);
        iO0 = i0; iO1 = i1; iO2 = i2; iO3 = i3;
        i0 += 32u; i1 += 32u; i2 += 32u; i3 += 32u;
        top2_pair(e00, e01, e10, e11, iE0, iE1, iE2, iE3,
                  &k1A, &k2A, &k1B, &k2B);
        y0 = *(const short8*)(W);                  // pair 2it+3 tiles
        y1 = *(const short8*)(W + 1024);
        // MFMA pair 2it+2 (x), then consume pair 2it+1 (pending o)
        asm("" : "+v"(x0), "+v"(x1));
        mfma8(x0, x1, V1A, V2A, V1B, V2B, cinit, &e00, &e01, &e10, &e11);
        iE0 = i0; iE1 = i1; iE2 = i2; iE3 = i3;
        i0 += 32u; i1 += 32u; i2 += 32u; i3 += 32u;
        top2_pair(o00, o01, o10, o11, iO0, iO1, iO2, iO3,
                  &k1A, &k2A, &k1B, &k2B);
        x0 = *(const short8*)(W + 2048);           // pair 2it+4 tiles
        x1 = *(const short8*)(W + 3072);
        W += 4096;
    }
    // tail: pending e = pair22; y = pair23 tiles (46,47); x = pair24 (48,49)
    asm("" : "+v"(y0), "+v"(y1));
    mfma8(y0, y1, V1A, V2A, V1B, V2B, cinit, &o00, &o01, &o10, &o11);
    iO0 = i0; iO1 = i1; iO2 = i2; iO3 = i3;
    i0 += 32u; i1 += 32u; i2 += 32u; i3 += 32u;
    top2_pair(e00, e01, e10, e11, iE0, iE1, iE2, iE3,
              &k1A, &k2A, &k1B, &k2B);
    asm("" : "+v"(x0), "+v"(x1));
    mfma8(x0, x1, V1A, V2A, V1B, V2B, cinit, &e00, &e01, &e10, &e11);
    iE0 = i0; iE1 = i1; iE2 = i2; iE3 = i3;
    top2_pair(o00, o01, o10, o11, iO0, iO1, iO2, iO3,
              &k1A, &k2A, &k1B, &k2B);
    top2_pair(e00, e01, e10, e11, iE0, iE1, iE2, iE3,
              &k1A, &k2A, &k1B, &k2B);

    // ---- epilogue: cross-quad top-2 merge, EXACT rescore from db_mag ----
    float tvB[ETLN], s2B;
#pragma unroll
    for (int e = 0; e < ETLN; ++e) tvB[e] = __shfl(tv[e], lane + 16);
    s2B = __shfl(s2px, lane + 16);

#pragma unroll
    for (int g = 0; g < 2; ++g) {
        uint p1 = g ? k1B : k1A;
        uint p2 = g ? k2B : k2A;
#pragma unroll
        for (int off = 16; off <= 32; off <<= 1) {
            uint o1 = (uint)__shfl_xor((int)p1, off);
            uint o2 = (uint)__shfl_xor((int)p2, off);
            uint n1 = p1 < o1 ? p1 : o1;
            uint mx = p1 < o1 ? o1 : p1;
            uint mn = p2 < o2 ? p2 : o2;
            p2 = mx < mn ? mx : mn;
            p1 = n1;
        }
        if (lane < 16) {
            int px = wbase + lane + (g ? 16 : 0);
            int j1 = (int)(p1 & 0xFFFu);
            int j2 = (int)(p2 & 0xFFFu);
            const float* tvx = g ? tvB : tv;
            float sx = g ? s2B : s2px;
            float w1[ETLN], w2[ETLN];
            atom_row(db_mag + (size_t)j1 * ETLN, mask, z, w1);
            atom_row(db_mag + (size_t)j2 * ETLN, mask, z, w2);
            float f1 = 0.f, f2 = 0.f;
#pragma unroll
            for (int e = 0; e < ETLN; ++e) {
                f1 = fmaf(w1[e], tvx[e], f1);
                f2 = fmaf(w2[e], tvx[e], f2);
            }
            u64 key1 = (((u64)fmono(f1 + sx)) << 32) | (uint)j1;
            u64 key2 = (((u64)fmono(f2 + sx)) << 32) | (uint)j2;
            partial[(size_t)blockIdx.y * NPIX + px] =
                key1 < key2 ? key1 : key2;
        }
    }
}

// finalize: min over 5 chunk keys, decode (monotone bits of f+s2, j)
__global__ __launch_bounds__(256) void finalize(
        const u64* __restrict__ partial, const float* __restrict__ t2s,
        const float* __restrict__ b1s, float* __restrict__ out) {
    int p = blockIdx.x * 256 + threadIdx.x;
    if (p >= NPIX) return;
    u64 m = partial[p];
#pragma unroll
    for (int c = 1; c < SCH; ++c) {
        u64 v = partial[(size_t)c * NPIX + p];
        m = v < m ? v : m;
    }
    int j = (int)(m & 0xFFFu);
    uint mb = (uint)(m >> 32);
    uint b = (mb & 0x80000000u) ? (mb ^ 0x80000000u) : ~mb;  // fmono^-1
    float val = __uint_as_float(b);                          // = f + s2
    out[p] = t2s[j];
    out[NPIX + p] = b1s[j];
    out[2 * NPIX + p] = sqrtf(fmaxf(val, 0.0f));
}

extern "C" void kernel_launch(void* const* d_in, const int* in_sizes, int n_in,
                              void* d_out, int out_size, void* d_ws, size_t ws_size,
                              hipStream_t stream) {
    const float* sig    = (const float*)d_in[0];  // [192,192,16]
    const float* db_mag = (const float*)d_in[1];  // [4000,16]
    const float* t2s    = (const float*)d_in[2];  // [4000]
    const float* b1s    = (const float*)d_in[3];  // [4000]
    const float* delta  = (const float*)d_in[4];  // [16]

    char* ws = (char*)d_ws;
    char* A1      = ws + OFF_A1;
    u64*  partial = (u64*)(ws + OFF_PART);

    prep_atoms<<<(DATOMS + 255) / 256, 256, 0, stream>>>(db_mag, delta, A1);
    dim3 grid(PXB, SCH);
    match_fused<<<grid, 256, 0, stream>>>(sig, db_mag, delta, A1, partial);
    finalize<<<PXB / 2, 256, 0, stream>>>(partial, t2s, b1s, (float*)d_out);
}